// Round 2
// baseline (318.229 us; speedup 1.0000x reference)
//
#include <hip/hip_runtime.h>

// CSTR gated-estimator trajectory cost — 2 lanes per sample, chain-trimmed.
// B=8192 samples, T=2048 sequential RK4 steps, N=2 states.
//
// Regime (rocprof rounds 0-1): latency-bound on the per-step dependency chain
// (per-step time insensitive to per-lane op count; VALU ~16%, occ 2.8%).
// Chain trims vs round-0 kernel:
//  1. Control tail removed from chain: Hs*u = kxh + d*kdx with
//     kxh = K~.xh, kdx = K~.(x-xh) precomputed BEFORE d resolves
//     (they overlap the previous step's exp/rcp). x' = fma(d,kdx,pf):
//     tail after d = 1 fma (was fma -> mul -> DPP -> add -> add).
//  2. Phi tree balanced: per-lane pure-own partial (no DPP wait) + cross
//     partial (starts at xo/ho arrival), each depth-3, instead of a 6-deep
//     serial fma chain. One partial-combine DPP+add remains on the chain.
//  3. Partner state (xo,ho) maintained via 2 DPP swaps issued right after
//     the updates; dxo derived locally (no third swap).
//  4. Cost accumulators: {Sum x_own^2, Sum x1x2, Sum d} only; Sum us^2
//     reconstructed at the end. RK4 collapsed analytically (affine plant):
//     x_own' = (1-2H)x_own + H*x_oth + H*u + C_own + w_own,
//     C_1 = +H^2/2, C_2 = -H^2. Sigmoid in exp2 domain (coeffs * -log2(e)).

#define T_STEPS 2048
#define BATCH   8192

__device__ __forceinline__ float swapf(float v) {
    // quad_perm [1,0,3,2]: swap adjacent lane pairs. bound_ctrl=1, full masks.
    return __int_as_float(__builtin_amdgcn_update_dpp(
        0, __float_as_int(v), 0xB1, 0xF, 0xF, true));
}

__global__ __launch_bounds__(64, 1) void cstr_kernel(
    const float* __restrict__ w,   // (B, 2, T)
    const float* __restrict__ K,   // (1, 2)
    const float* __restrict__ L,   // (4, 4)
    const float* __restrict__ M,   // (1, 4)
    const float* __restrict__ Mo,  // (1, 1)
    float* __restrict__ out)       // (B,)
{
    const int lane = threadIdx.x;
    const int p = lane & 1;                          // owned state index
    const int s = blockIdx.x * 32 + (lane >> 1);     // sample id

    constexpr float SC = -1.44269504088896340736f;   // -log2(e)
    constexpr float Hs = 0.01f;
    constexpr float Ad = 1.0f - 2.0f * Hs;           // 0.98
    constexpr float Rc = 0.1f;

    const float k1c = K[0], k2c = K[1];
    // folded symmetric coefficients, pre-scaled into exp2 domain
    const float s11 = L[0] * SC;
    const float s12 = (L[1] + L[4]) * SC;
    const float s13 = (L[2] + L[8]) * SC;
    const float s14 = (L[3] + L[12]) * SC;
    const float s22 = L[5] * SC;
    const float s23 = (L[6] + L[9]) * SC;
    const float s24 = (L[7] + L[13]) * SC;
    const float s33 = L[10] * SC;
    const float s34 = (L[11] + L[14]) * SC;
    const float s44 = L[15] * SC;
    const float m1 = M[0] * SC, m2 = M[1] * SC, m3 = M[2] * SC, m4 = M[3] * SC;
    const float c0s = Mo[0] * SC;

    // per-lane own-space constants.
    // pown = x*(A1*x + A2*h + A3) + h*(A4*h + A5)
    // cr   = x*(B1*xo + B2*ho) + B3*h*ho + B4
    // lane0 (own=1): pown covers s11,s13,m1,s33,m3; cr covers s14,s34,c0
    // lane1 (own=2): pown covers s22,s24,m2,s44,m4; cr covers s12,s23
    float A1, A2, A3, A4, A5, B1, B2, B3, B4;
    if (p == 0) { A1 = s11; A2 = s13; A3 = m1; A4 = s33; A5 = m3;
                  B1 = 0.f; B2 = s14; B3 = s34; B4 = c0s; }
    else        { A1 = s22; A2 = s24; A3 = m2; A4 = s44; A5 = m4;
                  B1 = s12; B2 = s23; B3 = 0.f; B4 = 0.f; }
    const float kown = p ? k2c : k1c;
    const float KA = Hs * kown;                  // Hs * K_own
    const float KB = Hs * (p ? k1c : k2c);       // Hs * K_oth
    const float Cw = p ? (-Hs * Hs) : (0.5f * Hs * Hs);

    // ---- state (own + mirrored partner copies kept fresh via DPP) ----
    float x  = p ? 0.0f : 1.0f;   // x0 = (1, 0)
    float h  = x;
    float xo = p ? 1.0f : 0.0f;
    float ho = xo;
    float accO = 0.0f;            // sum of own-state x^2
    float accXY = 0.0f;           // sum x1*x2 (identical on both lanes)
    float accD = 0.0f;            // sum delta (identical on both lanes)

    auto step = [&](float wv, bool first, bool cost) {
        // ---- off-chain control precompute (overlaps previous exp/rcp) ----
        float dx  = x - h;
        float dxo = xo - ho;
        float kdx = fmaf(KA, dx, KB * dxo);      // Hs*K.(x - xh)
        float kxh = fmaf(KA, h, KB * ho);        // Hs*K.xh (pre-update)
        float wck = wv + Cw + kxh;
        float pf  = fmaf(Ad, x, fmaf(Hs, xo, wck));

        float d;
        if (first) {
            d = 1.0f;             // i==0: gate forced, x_hat frozen (x==h)
        } else {
            float pown = fmaf(x, fmaf(A1, x, fmaf(A2, h, A3)),
                              h * fmaf(A4, h, A5));
            float hho  = h * ho;
            float cr   = fmaf(x, fmaf(B1, xo, B2 * ho), fmaf(B3, hho, B4));
            float part = pown + cr;
            float ph   = part + swapf(part);     // full phi (exp2 domain)
            float E    = __builtin_amdgcn_exp2f(ph);     // = exp(-phi)
            d = __builtin_amdgcn_rcpf(1.0f + E);         // sigmoid(phi)
        }
        if (cost) {               // stage cost uses PRE-update x, this step's d
            accO  = fmaf(x, x, accO);
            accXY = fmaf(x, xo, accXY);
            accD += d;
        }
        // u = K.xh_new -> Hs*u = kxh + d*kdx (kxh folded into pf already)
        x = fmaf(d, kdx, pf);
        h = fmaf(d, dx, h);
        xo = swapf(x);
        ho = swapf(h);
    };

    auto chunk = [&](const float4* buf, bool first, bool lastchunk) {
        #pragma unroll
        for (int q = 0; q < 4; ++q) {
            float4 a = buf[q];
            step(a.x, first && (q == 0), true);
            step(a.y, false, true);
            step(a.z, false, true);
            step(a.w, false, !(lastchunk && (q == 3)));  // t=T-1: no stage cost
        }
    };

    // own-row stream: T floats = 512 float4 = 128 chunks of 16 steps
    const float4* r = reinterpret_cast<const float4*>(
        w + ((size_t)s * 2 + p) * T_STEPS);

    float4 Abuf[4], Bbuf[4];
    #pragma unroll
    for (int q = 0; q < 4; ++q) Abuf[q] = r[q];        // chunk 0
    #pragma unroll
    for (int q = 0; q < 4; ++q) Bbuf[q] = r[4 + q];    // chunk 1

    chunk(Abuf, true, false);                          // chunk 0 (step 0 special)

    for (int i = 0; i < 63; ++i) {                     // chunks 1..126
        const float4* pa = r + (size_t)(2 + 2 * i) * 4;
        #pragma unroll
        for (int q = 0; q < 4; ++q) Abuf[q] = pa[q];   // prefetch chunk 2+2i
        chunk(Bbuf, false, false);                     // process chunk 1+2i
        const float4* pb = r + (size_t)(3 + 2 * i) * 4;
        #pragma unroll
        for (int q = 0; q < 4; ++q) Bbuf[q] = pb[q];   // prefetch chunk 3+2i
        chunk(Abuf, false, false);                     // process chunk 2+2i
    }
    chunk(Bbuf, false, true);                          // chunk 127 (last step: no cost)

    // Sum us^2 = k1^2*Sx1^2 + k2^2*Sx2^2 + 2 k1 k2*Sx1x2, assembled pairwise:
    // per-lane t = kown^2*accO + k1k2*accXY; t + swap(t) = full sum.
    float tt  = fmaf(kown * kown, accO, (k1c * k2c) * accXY);
    float us2 = tt + swapf(tt);
    float qq  = accO + swapf(accO);              // Sum (x1^2 + x2^2)
    float term = 10.0f * fmaf(x, x, xo * xo);    // terminal, same on both lanes
    float J = qq + fmaf(Rc, us2, accD + term);
    if (p == 0) out[s] = J;
}

extern "C" void kernel_launch(void* const* d_in, const int* in_sizes, int n_in,
                              void* d_out, int out_size, void* d_ws, size_t ws_size,
                              hipStream_t stream) {
    const float* w  = (const float*)d_in[0];
    const float* K  = (const float*)d_in[1];
    const float* L  = (const float*)d_in[2];
    const float* M  = (const float*)d_in[3];
    const float* Mo = (const float*)d_in[4];
    float* out = (float*)d_out;

    // 8192 samples * 2 lanes = 16384 threads = 256 blocks of 64 (1 wave each)
    hipLaunchKernelGGL(cstr_kernel, dim3(BATCH * 2 / 64), dim3(64), 0, stream,
                       w, K, L, M, Mo, out);
}